// Round 10
// baseline (120.412 us; speedup 1.0000x reference)
//
#include <hip/hip_runtime.h>

#define NDIM 1024
#define CH 16
#define ROW_F4 4096   // float4 per W row (1024*16/4)

__device__ inline float4 f4add(float4 a, float4 b) {
    return make_float4(a.x + b.x, a.y + b.y, a.z + b.z, a.w + b.w);
}
__device__ inline float4 f4zero() { return make_float4(0.f, 0.f, 0.f, 0.f); }

// ---------------------------------------------------------------------------
// k_fused (round-8 proven): ONE pass over W -> row partials (16 j-chunks),
// col partials (128 i-chunks), per-tile totals. Block = 8 rows x 64 cols.
// LDS 33 KB -> 4 blocks/CU. Partials live in out0 scratch.
// ---------------------------------------------------------------------------
__global__ __launch_bounds__(256) void k_fused(const float* __restrict__ W1,
                                               const float* __restrict__ W2,
                                               float* __restrict__ rowpart,
                                               float* __restrict__ colpart,
                                               float* __restrict__ tiletot) {
    int t  = threadIdx.x;
    int jt = blockIdx.x, it = blockIdx.y, z = blockIdx.z;
    const float4* base = (const float4*)(z ? W2 : W1)
                       + (size_t)it * 8 * ROW_F4 + jt * 256 + t;
    __shared__ float4 tile[8][258];
    __shared__ float4 rtot[32];
    float4 colacc = f4zero();
#pragma unroll
    for (int r = 0; r < 8; ++r) {
        float4 v = base[(size_t)r * ROW_F4];
        colacc = f4add(colacc, v);
        tile[r][t] = v;
    }
    ((float4*)colpart)[(size_t)(z * 128 + it) * 4096 + jt * 256 + t] = colacc;
    __syncthreads();
    if (t < 32) {   // row partials: r = t>>2, cq = t&3
        int r = t >> 2, cq = t & 3;
        float4 s = f4zero();
#pragma unroll
        for (int jl = 0; jl < 64; ++jl) s = f4add(s, tile[r][jl * 4 + cq]);
        ((float4*)rowpart)[(size_t)(z * 16 + jt) * 4096 + (it * 8 + r) * 4 + cq] = s;
        rtot[t] = s;
    }
    __syncthreads();
    if (t < 4) {    // tile total (16 ch)
        float4 s = f4zero();
#pragma unroll
        for (int r = 0; r < 8; ++r) s = f4add(s, rtot[r * 4 + t]);
        ((float4*)tiletot)[(size_t)(z * 2048 + it * 16 + jt) * 4 + t] = s;
    }
}

// ---------------------------------------------------------------------------
// k_reduce (round-8 proven): parallel, coalesced reduction of all partials.
// ---------------------------------------------------------------------------
__global__ __launch_bounds__(256) void k_reduce(const float* __restrict__ rowpart,
                                                const float* __restrict__ colpart,
                                                const float* __restrict__ tiletot,
                                                const float* __restrict__ b1,
                                                const float* __restrict__ b2,
                                                float* __restrict__ rowsumF,
                                                float* __restrict__ colsumF,
                                                float* __restrict__ sums) {
    int t = threadIdx.x;
    int b = blockIdx.x;
    if (b < 128) {
        const float4* cp = (const float4*)colpart;
        int o = b * 64 + (t & 63);
        int p = t >> 6;
        int z = o >> 12, rem = o & 4095;
        float4 s = f4zero();
#pragma unroll 8
        for (int k = 0; k < 32; ++k)
            s = f4add(s, cp[(size_t)(z * 128 + p * 32 + k) * 4096 + rem]);
        __shared__ float4 lds[256];
        lds[t] = s;
        __syncthreads();
        if (t < 64) {
            float4 r = f4add(f4add(lds[t], lds[t + 64]),
                             f4add(lds[t + 128], lds[t + 192]));
            ((float4*)colsumF)[o] = r;
        }
    } else if (b < 160) {
        const float4* rp = (const float4*)rowpart;
        int o = (b - 128) * 256 + t;
        int z = o >> 12, rem = o & 4095;
        float4 s = f4zero();
#pragma unroll
        for (int k = 0; k < 16; ++k)
            s = f4add(s, rp[(size_t)(z * 16 + k) * 4096 + rem]);
        ((float4*)rowsumF)[o] = s;
    } else if (b == 160) {
        int c = t & 15, p = (t >> 4) & 7, z = t >> 7;
        float s = 0.f;
#pragma unroll 8
        for (int m = 0; m < 256; ++m)
            s += tiletot[(size_t)(z * 2048 + p * 256 + m) * 16 + c];
        __shared__ float ldsA[2][8][16];
        ldsA[z][p][c] = s;
        __syncthreads();
        if (t < 32) {
            int zz = t >> 4, cc = t & 15;
            float r = 0.f;
#pragma unroll
            for (int q = 0; q < 8; ++q) r += ldsA[zz][q][cc];
            sums[zz * 16 + cc] = r;
        }
    } else {
        int w = b - 161;
        const float* src = w ? b2 : b1;
        int c = t & 15, p = t >> 4;
        float s = 0.f;
#pragma unroll 8
        for (int m = 0; m < 64; ++m)
            s += src[(size_t)(p * 64 + m) * 16 + c];
        __shared__ float ldsB[16][16];
        ldsB[p][c] = s;
        __syncthreads();
        if (t < 16) {
            float r = 0.f;
#pragma unroll
            for (int q = 0; q < 16; ++q) r += ldsB[q][t];
            sums[32 + w * 16 + t] = r;
        }
    }
}

// ---------------------------------------------------------------------------
// k_smalls (round-8 proven): all O(N) outputs from finalized sums.
// ---------------------------------------------------------------------------
__global__ __launch_bounds__(256) void k_smalls(const float* __restrict__ rowsum,
                                                const float* __restrict__ colsum,
                                                const float* __restrict__ sums,
                                                const float* __restrict__ b1,
                                                const float* __restrict__ b2,
                                                const float* __restrict__ th0,
                                                const float* __restrict__ th1,
                                                const float* __restrict__ th2,
                                                const float* __restrict__ th3,
                                                const float* __restrict__ bias0,
                                                const float* __restrict__ bias1,
                                                const float* __restrict__ bias2,
                                                const float* __restrict__ bias3,
                                                float* __restrict__ R0, float* __restrict__ C0,
                                                float* __restrict__ R1, float* __restrict__ C1,
                                                float* __restrict__ out2, float* __restrict__ out3) {
    int gt = blockIdx.x * 256 + threadIdx.x;
    int i = gt >> 4, o = gt & 15;
    const float* rs1 = rowsum + i * 16;
    const float* rs2 = rowsum + 16384 + i * 16;
    const float* cs1 = colsum + i * 16;
    const float* cs2 = colsum + 16384 + i * 16;
    const float* b1i = b1 + i * 16;
    const float* b2i = b2 + i * 16;
    float r0 = 0.f, c0a = 0.f, r1 = 0.f, c1a = 0.f, o2 = 0.f, o3 = 0.f;
    float k0 = 0.f, k1 = 0.f, k2 = 0.f, k3 = 0.f;
#pragma unroll
    for (int c = 0; c < 16; ++c) {
        float sW1 = sums[c], sW2 = sums[16 + c], sb1 = sums[32 + c], sb2 = sums[48 + c];
        r0  += rs1[c] * th0[(1 * 16 + c) * 16 + o];
        c0a += cs1[c] * th0[(2 * 16 + c) * 16 + o]
             + rs2[c] * th0[(4 * 16 + c) * 16 + o]
             + b1i[c] * th0[(6 * 16 + c) * 16 + o];
        k0  += sW1 * th0[(3 * 16 + c) * 16 + o] + sW2 * th0[(5 * 16 + c) * 16 + o]
             + sb1 * th0[(7 * 16 + c) * 16 + o] + sb2 * th0[(8 * 16 + c) * 16 + o];
        r1  += cs1[c] * th1[(0 * 16 + c) * 16 + o]
             + rs2[c] * th1[(3 * 16 + c) * 16 + o]
             + b1i[c] * th1[(6 * 16 + c) * 16 + o];
        c1a += cs2[c] * th1[(4 * 16 + c) * 16 + o]
             + b2i[c] * th1[(8 * 16 + c) * 16 + o];
        k1  += sW1 * th1[(1 * 16 + c) * 16 + o] + sW2 * th1[(5 * 16 + c) * 16 + o]
             + sb1 * th1[(7 * 16 + c) * 16 + o] + sb2 * th1[(9 * 16 + c) * 16 + o];
        o2  += cs1[c] * th2[(0 * 16 + c) * 16 + o]
             + rs2[c] * th2[(2 * 16 + c) * 16 + o]
             + b1i[c] * th2[(4 * 16 + c) * 16 + o];
        k2  += sW1 * th2[(1 * 16 + c) * 16 + o] + sW2 * th2[(3 * 16 + c) * 16 + o]
             + sb1 * th2[(5 * 16 + c) * 16 + o] + sb2 * th2[(6 * 16 + c) * 16 + o];
        o3  += cs2[c] * th3[(1 * 16 + c) * 16 + o]
             + b2i[c] * th3[(4 * 16 + c) * 16 + o];
        k3  += sW1 * th3[(0 * 16 + c) * 16 + o] + sW2 * th3[(2 * 16 + c) * 16 + o]
             + sb1 * th3[(3 * 16 + c) * 16 + o] + sb2 * th3[(5 * 16 + c) * 16 + o];
    }
    R0[gt]   = r0;
    C0[gt]   = c0a + k0 + bias0[o];
    R1[gt]   = r1;
    C1[gt]   = c1a + k1 + bias1[o];
    out2[gt] = o2 + k2 + bias2[o];
    out3[gt] = o3 + k3 + bias3[o];
}

// ---------------------------------------------------------------------------
// k_main v3: 2 j's per thread -> θ LDS broadcast traffic per CU halves
// (the round-8 limiter). Direct global I/O (128B contiguous per thread;
// quad-group instructions merge in L1). θ/R in LDS, one barrier total.
//   out[i,j,:] = W[i,j,:]·θ + R[i] + C[j]
// ---------------------------------------------------------------------------
__global__ __launch_bounds__(256) void k_main(const float* __restrict__ W1,
                                              const float* __restrict__ W2,
                                              const float* __restrict__ R0,
                                              const float* __restrict__ C0,
                                              const float* __restrict__ R1,
                                              const float* __restrict__ C1,
                                              const float* __restrict__ th0,
                                              const float* __restrict__ th1,
                                              float* __restrict__ out0,
                                              float* __restrict__ out1) {
    int z = blockIdx.z;
    const float* __restrict__ W  = z ? W2 : W1;
    const float* __restrict__ R  = z ? R1 : R0;
    const float* __restrict__ Cc = z ? C1 : C0;
    const float* __restrict__ TH = z ? th1 : th0;
    float* __restrict__ out      = z ? out1 : out0;

    int t  = threadIdx.x;
    int i  = blockIdx.y;
    int jb = blockIdx.x * 512;        // this block: 512 j's, 2 per thread

    __shared__ float th[256];
    __shared__ float r[16];
    th[t] = TH[t];
    if (t < 16) r[t] = R[i * 16 + t];
    __syncthreads();

    // thread covers f4 indices [jb*4 + t*8, +8) = 2 consecutive j's (128 B)
    const float4* Wp = (const float4*)W  + (size_t)i * 4096 + jb * 4 + t * 8;
    const float4* Cp = (const float4*)Cc + (size_t)jb * 4 + t * 8;
    float4*       Op = (float4*)out      + (size_t)i * 4096 + jb * 4 + t * 8;

    float4 x[8];
#pragma unroll
    for (int k = 0; k < 8; ++k) x[k] = Wp[k];

    float acc[2][16];
#pragma unroll
    for (int jj = 0; jj < 2; ++jj) {
#pragma unroll
        for (int q = 0; q < 4; ++q) {
            float4 cv = Cp[jj * 4 + q];
            acc[jj][q * 4 + 0] = cv.x + r[q * 4 + 0];
            acc[jj][q * 4 + 1] = cv.y + r[q * 4 + 1];
            acc[jj][q * 4 + 2] = cv.z + r[q * 4 + 2];
            acc[jj][q * 4 + 3] = cv.w + r[q * 4 + 3];
        }
    }
#pragma unroll
    for (int c = 0; c < 16; ++c) {
        float tv[16];                 // th row c: 4 broadcast ds_read_b128
#pragma unroll
        for (int o = 0; o < 16; ++o) tv[o] = th[c * 16 + o];
#pragma unroll
        for (int jj = 0; jj < 2; ++jj) {
            float4 xd = x[jj * 4 + (c >> 2)];
            float xv = ((c & 3) == 0) ? xd.x : ((c & 3) == 1) ? xd.y
                     : ((c & 3) == 2) ? xd.z : xd.w;   // folds: c is constant
#pragma unroll
            for (int o = 0; o < 16; ++o) acc[jj][o] += xv * tv[o];
        }
    }
#pragma unroll
    for (int jj = 0; jj < 2; ++jj)
#pragma unroll
        for (int q = 0; q < 4; ++q)
            Op[jj * 4 + q] = make_float4(acc[jj][q * 4 + 0], acc[jj][q * 4 + 1],
                                         acc[jj][q * 4 + 2], acc[jj][q * 4 + 3]);
}

extern "C" void kernel_launch(void* const* d_in, const int* in_sizes, int n_in,
                              void* d_out, int out_size, void* d_ws, size_t ws_size,
                              hipStream_t stream) {
    // input order (interleaved theta/bias):
    // 0:W1 1:W2 2:b1 3:b2 4:theta_0 5:bias_0 6:theta_1 7:bias_1
    // 8:theta_2 9:bias_2 10:theta_3 11:bias_3
    const float* W1    = (const float*)d_in[0];
    const float* W2    = (const float*)d_in[1];
    const float* b1    = (const float*)d_in[2];
    const float* b2    = (const float*)d_in[3];
    const float* th0   = (const float*)d_in[4];
    const float* bias0 = (const float*)d_in[5];
    const float* th1   = (const float*)d_in[6];
    const float* bias1 = (const float*)d_in[7];
    const float* th2   = (const float*)d_in[8];
    const float* bias2 = (const float*)d_in[9];
    const float* th3   = (const float*)d_in[10];
    const float* bias3 = (const float*)d_in[11];

    float* out  = (float*)d_out;
    float* out0 = out;
    float* out1 = out + (size_t)NDIM * NDIM * CH;
    float* out2 = out1 + (size_t)NDIM * NDIM * CH;
    float* out3 = out2 + (size_t)NDIM * CH;

    // scratch in the (not-yet-written) out0 region (19.1 MB of 64 MB):
    float* rowpart = out0;                       // [2][16][1024][16]  = 524288
    float* colpart = out0 + 524288;              // [2][128][1024][16] = 4194304
    float* tiletot = out0 + 4718592;             // [2][2048][16]      = 65536

    // workspace: 131,136 floats = 524,544 B (proven budget)
    float* ws      = (float*)d_ws;
    float* rowsumF = ws;                         // [2][1024][16] = 32768
    float* colsumF = ws + 32768;                 // [2][1024][16] = 32768
    float* sums    = ws + 65536;                 // [4][16] = 64
    float* R0      = ws + 65600;                 // 16384 each
    float* C0      = R0 + 16384;
    float* R1      = C0 + 16384;
    float* C1      = R1 + 16384;

    k_fused<<<dim3(16, 128, 2), dim3(256), 0, stream>>>(W1, W2, rowpart, colpart, tiletot);
    k_reduce<<<dim3(163), dim3(256), 0, stream>>>(rowpart, colpart, tiletot, b1, b2,
                                                  rowsumF, colsumF, sums);
    k_smalls<<<dim3(64), dim3(256), 0, stream>>>(rowsumF, colsumF, sums, b1, b2,
                                                 th0, th1, th2, th3,
                                                 bias0, bias1, bias2, bias3,
                                                 R0, C0, R1, C1, out2, out3);
    k_main<<<dim3(2, NDIM, 2), dim3(256), 0, stream>>>(W1, W2, R0, C0, R1, C1,
                                                       th0, th1 + 2 * 256,
                                                       out0, out1);
}

// Round 11
// 115.403 us; speedup vs baseline: 1.0434x; 1.0434x over previous
//
#include <hip/hip_runtime.h>

#define NDIM 1024
#define CH 16
#define ROW_F4 4096   // float4 per W row (1024*16/4)

__device__ inline float4 f4add(float4 a, float4 b) {
    return make_float4(a.x + b.x, a.y + b.y, a.z + b.z, a.w + b.w);
}
__device__ inline float4 f4zero() { return make_float4(0.f, 0.f, 0.f, 0.f); }

// ---------------------------------------------------------------------------
// k_fused (round-8 proven, verbatim): ONE pass over W -> row partials
// (16 j-chunks), col partials (128 i-chunks), per-tile totals.
// Block = 8 rows x 64 cols. LDS 33 KB -> 4 blocks/CU. Partials in out0.
// ---------------------------------------------------------------------------
__global__ __launch_bounds__(256) void k_fused(const float* __restrict__ W1,
                                               const float* __restrict__ W2,
                                               float* __restrict__ rowpart,
                                               float* __restrict__ colpart,
                                               float* __restrict__ tiletot) {
    int t  = threadIdx.x;
    int jt = blockIdx.x, it = blockIdx.y, z = blockIdx.z;
    const float4* base = (const float4*)(z ? W2 : W1)
                       + (size_t)it * 8 * ROW_F4 + jt * 256 + t;
    __shared__ float4 tile[8][258];
    __shared__ float4 rtot[32];
    float4 colacc = f4zero();
#pragma unroll
    for (int r = 0; r < 8; ++r) {
        float4 v = base[(size_t)r * ROW_F4];
        colacc = f4add(colacc, v);
        tile[r][t] = v;
    }
    ((float4*)colpart)[(size_t)(z * 128 + it) * 4096 + jt * 256 + t] = colacc;
    __syncthreads();
    if (t < 32) {   // row partials: r = t>>2, cq = t&3
        int r = t >> 2, cq = t & 3;
        float4 s = f4zero();
#pragma unroll
        for (int jl = 0; jl < 64; ++jl) s = f4add(s, tile[r][jl * 4 + cq]);
        ((float4*)rowpart)[(size_t)(z * 16 + jt) * 4096 + (it * 8 + r) * 4 + cq] = s;
        rtot[t] = s;
    }
    __syncthreads();
    if (t < 4) {    // tile total (16 ch)
        float4 s = f4zero();
#pragma unroll
        for (int r = 0; r < 8; ++r) s = f4add(s, rtot[r * 4 + t]);
        ((float4*)tiletot)[(size_t)(z * 2048 + it * 16 + jt) * 4 + t] = s;
    }
}

// ---------------------------------------------------------------------------
// k_mid: fully-parallel finalize + global sums + all O(N) outputs (64 blocks,
// 16 i's per block). Global sums computed redundantly per block with ALL 256
// threads from tiletot/b (L2-resident).
// ---------------------------------------------------------------------------
__global__ __launch_bounds__(256) void k_mid(const float* __restrict__ rowpart,
                                             const float* __restrict__ colpart,
                                             const float* __restrict__ tiletot,
                                             const float* __restrict__ b1,
                                             const float* __restrict__ b2,
                                             const float* __restrict__ th0,
                                             const float* __restrict__ th1,
                                             const float* __restrict__ th2,
                                             const float* __restrict__ th3,
                                             const float* __restrict__ bias0,
                                             const float* __restrict__ bias1,
                                             const float* __restrict__ bias2,
                                             const float* __restrict__ bias3,
                                             float* __restrict__ R0, float* __restrict__ C0,
                                             float* __restrict__ R1, float* __restrict__ C1,
                                             float* __restrict__ out2, float* __restrict__ out3) {
    int t  = threadIdx.x;
    int i0 = blockIdx.x * 16;
    __shared__ float sums[64];                  // [W1|W2|b1|b2][16]
    __shared__ float ldsA[2][8][16], ldsB[2][8][16];
    __shared__ float Ars1[16][16], Ars2[16][16], Acs1[16][16], Acs2[16][16];

    // Step A: partial global sums, all 256 threads: (z, p, c)
    {
        int z = t >> 7, c = t & 15, p = (t >> 4) & 7;
        float s = 0.f;
#pragma unroll 8
        for (int m = 0; m < 256; ++m)
            s += tiletot[(size_t)(z * 2048 + p * 256 + m) * 16 + c];
        ldsA[z][p][c] = s;
        const float* bb = z ? b2 : b1;
        s = 0.f;
#pragma unroll 8
        for (int m = 0; m < 128; ++m)
            s += bb[(size_t)(p * 128 + m) * 16 + c];
        ldsB[z][p][c] = s;
    }
    // Step B: finalize row/col sums for this block's 16 i's
    int il = t >> 4, o = t & 15, i = i0 + il;
    {
        float s1 = 0.f, s2 = 0.f, s3 = 0.f, s4 = 0.f;
#pragma unroll 4
        for (int k = 0; k < 16; ++k) {
            s1 += rowpart[(size_t)k * 16384 + i * 16 + o];
            s2 += rowpart[(size_t)(16 + k) * 16384 + i * 16 + o];
        }
#pragma unroll 8
        for (int k = 0; k < 128; ++k) {
            s3 += colpart[(size_t)k * 16384 + i * 16 + o];
            s4 += colpart[(size_t)(128 + k) * 16384 + i * 16 + o];
        }
        Ars1[il][o] = s1; Ars2[il][o] = s2; Acs1[il][o] = s3; Acs2[il][o] = s4;
    }
    __syncthreads();
    if (t < 32) {
        int z = t >> 4, cc = t & 15;
        float r = 0.f;
#pragma unroll
        for (int q = 0; q < 8; ++q) r += ldsA[z][q][cc];
        sums[z * 16 + cc] = r;
    } else if (t < 64) {
        int z = (t - 32) >> 4, cc = t & 15;
        float r = 0.f;
#pragma unroll
        for (int q = 0; q < 8; ++q) r += ldsB[z][q][cc];
        sums[32 + z * 16 + cc] = r;
    }
    __syncthreads();

    // Step C: smalls math. Thread -> (il, o). theta [k][c][o] at k*256+c*16+o
    const float* b1i = b1 + i * 16;
    const float* b2i = b2 + i * 16;
    float r0 = 0.f, c0a = 0.f, r1 = 0.f, c1a = 0.f, o2 = 0.f, o3 = 0.f;
    float k0 = 0.f, k1 = 0.f, k2 = 0.f, k3 = 0.f;
#pragma unroll
    for (int c = 0; c < 16; ++c) {
        float sW1 = sums[c], sW2 = sums[16 + c], sb1 = sums[32 + c], sb2 = sums[48 + c];
        float rs1 = Ars1[il][c], rs2 = Ars2[il][c];
        float cs1 = Acs1[il][c], cs2 = Acs2[il][c];
        float vb1 = b1i[c], vb2 = b2i[c];
        r0  += rs1 * th0[(1 * 16 + c) * 16 + o];
        c0a += cs1 * th0[(2 * 16 + c) * 16 + o]
             + rs2 * th0[(4 * 16 + c) * 16 + o]
             + vb1 * th0[(6 * 16 + c) * 16 + o];
        k0  += sW1 * th0[(3 * 16 + c) * 16 + o] + sW2 * th0[(5 * 16 + c) * 16 + o]
             + sb1 * th0[(7 * 16 + c) * 16 + o] + sb2 * th0[(8 * 16 + c) * 16 + o];
        r1  += cs1 * th1[(0 * 16 + c) * 16 + o]
             + rs2 * th1[(3 * 16 + c) * 16 + o]
             + vb1 * th1[(6 * 16 + c) * 16 + o];
        c1a += cs2 * th1[(4 * 16 + c) * 16 + o]
             + vb2 * th1[(8 * 16 + c) * 16 + o];
        k1  += sW1 * th1[(1 * 16 + c) * 16 + o] + sW2 * th1[(5 * 16 + c) * 16 + o]
             + sb1 * th1[(7 * 16 + c) * 16 + o] + sb2 * th1[(9 * 16 + c) * 16 + o];
        o2  += cs1 * th2[(0 * 16 + c) * 16 + o]
             + rs2 * th2[(2 * 16 + c) * 16 + o]
             + vb1 * th2[(4 * 16 + c) * 16 + o];
        k2  += sW1 * th2[(1 * 16 + c) * 16 + o] + sW2 * th2[(3 * 16 + c) * 16 + o]
             + sb1 * th2[(5 * 16 + c) * 16 + o] + sb2 * th2[(6 * 16 + c) * 16 + o];
        o3  += cs2 * th3[(1 * 16 + c) * 16 + o]
             + vb2 * th3[(4 * 16 + c) * 16 + o];
        k3  += sW1 * th3[(0 * 16 + c) * 16 + o] + sW2 * th3[(2 * 16 + c) * 16 + o]
             + sb1 * th3[(3 * 16 + c) * 16 + o] + sb2 * th3[(5 * 16 + c) * 16 + o];
    }
    int gt = i * 16 + o;
    R0[gt]   = r0;
    C0[gt]   = c0a + k0 + bias0[o];
    R1[gt]   = r1;
    C1[gt]   = c1a + k1 + bias1[o];
    out2[gt] = o2 + k2 + bias2[o];
    out3[gt] = o3 + k3 + bias3[o];
}

// ---------------------------------------------------------------------------
// k_main v4: r8's proven LDS-staged CONTIGUOUS I/O + 2 j's per thread via TWO
// stage buffers sharing one tv[] per c — halves the θ LDS-broadcast cost per
// byte moved (the r8 limiter). 512 j per block; LDS 41.3 KB -> 3 blocks/CU.
//   out[i,j,:] = W[i,j,:]·θ + R[i] + C[j]
// ---------------------------------------------------------------------------
__global__ __launch_bounds__(256) void k_main(const float* __restrict__ W1,
                                              const float* __restrict__ W2,
                                              const float* __restrict__ R0,
                                              const float* __restrict__ C0,
                                              const float* __restrict__ R1,
                                              const float* __restrict__ C1,
                                              const float* __restrict__ th0,
                                              const float* __restrict__ th1,
                                              float* __restrict__ out0,
                                              float* __restrict__ out1) {
    int z = blockIdx.z;
    const float* __restrict__ W  = z ? W2 : W1;
    const float* __restrict__ R  = z ? R1 : R0;
    const float* __restrict__ Cc = z ? C1 : C0;
    const float* __restrict__ TH = z ? th1 : th0;
    float* __restrict__ out      = z ? out1 : out0;

    int t  = threadIdx.x;
    int i  = blockIdx.y;
    int jb = blockIdx.x * 512;        // block covers 512 j's

    __shared__ float4 xsA[1280];      // j's [jb, jb+256),   idx = 5*jl + k
    __shared__ float4 xsB[1280];      // j's [jb+256,jb+512)
    __shared__ float  th[256];
    __shared__ float  r[16];

    const float4* Wf4 = (const float4*)W + (size_t)i * 4096 + jb * 4;
    float4*       Of4 = (float4*)out    + (size_t)i * 4096 + jb * 4;

    th[t] = TH[t];
    if (t < 16) r[t] = R[i * 16 + t];
#pragma unroll
    for (int q = 0; q < 4; ++q) {     // contiguous 1KB-per-wave loads
        int g = t + 256 * q;
        xsA[5 * (g >> 2) + (g & 3)] = Wf4[g];
        xsB[5 * (g >> 2) + (g & 3)] = Wf4[1024 + g];
    }
    __syncthreads();

    float xA[16], xB[16];
#pragma unroll
    for (int k = 0; k < 4; ++k) {
        float4 va = xsA[5 * t + k];
        float4 vb = xsB[5 * t + k];
        xA[4 * k] = va.x; xA[4 * k + 1] = va.y; xA[4 * k + 2] = va.z; xA[4 * k + 3] = va.w;
        xB[4 * k] = vb.x; xB[4 * k + 1] = vb.y; xB[4 * k + 2] = vb.z; xB[4 * k + 3] = vb.w;
    }
    const float4* cjA = (const float4*)(Cc + (size_t)(jb + t) * 16);
    const float4* cjB = (const float4*)(Cc + (size_t)(jb + 256 + t) * 16);
    float accA[16], accB[16];
#pragma unroll
    for (int q = 0; q < 4; ++q) {
        float4 ca = cjA[q], cb = cjB[q];
        accA[q * 4 + 0] = ca.x + r[q * 4 + 0]; accB[q * 4 + 0] = cb.x + r[q * 4 + 0];
        accA[q * 4 + 1] = ca.y + r[q * 4 + 1]; accB[q * 4 + 1] = cb.y + r[q * 4 + 1];
        accA[q * 4 + 2] = ca.z + r[q * 4 + 2]; accB[q * 4 + 2] = cb.z + r[q * 4 + 2];
        accA[q * 4 + 3] = ca.w + r[q * 4 + 3]; accB[q * 4 + 3] = cb.w + r[q * 4 + 3];
    }
#pragma unroll
    for (int c = 0; c < 16; ++c) {
        float tv[16];                 // 4 broadcast b128 reads, shared by both j's
#pragma unroll
        for (int o = 0; o < 16; ++o) tv[o] = th[c * 16 + o];
        float xa = xA[c], xb = xB[c];
#pragma unroll
        for (int o = 0; o < 16; ++o) {
            accA[o] += xa * tv[o];
            accB[o] += xb * tv[o];
        }
    }
    __syncthreads();                  // all xs reads done
#pragma unroll
    for (int k = 0; k < 4; ++k) {
        xsA[5 * t + k] = make_float4(accA[4 * k], accA[4 * k + 1],
                                     accA[4 * k + 2], accA[4 * k + 3]);
        xsB[5 * t + k] = make_float4(accB[4 * k], accB[4 * k + 1],
                                     accB[4 * k + 2], accB[4 * k + 3]);
    }
    __syncthreads();
#pragma unroll
    for (int q = 0; q < 4; ++q) {     // contiguous stores
        int g = t + 256 * q;
        Of4[g]        = xsA[5 * (g >> 2) + (g & 3)];
        Of4[1024 + g] = xsB[5 * (g >> 2) + (g & 3)];
    }
}

extern "C" void kernel_launch(void* const* d_in, const int* in_sizes, int n_in,
                              void* d_out, int out_size, void* d_ws, size_t ws_size,
                              hipStream_t stream) {
    // input order (interleaved theta/bias):
    // 0:W1 1:W2 2:b1 3:b2 4:theta_0 5:bias_0 6:theta_1 7:bias_1
    // 8:theta_2 9:bias_2 10:theta_3 11:bias_3
    const float* W1    = (const float*)d_in[0];
    const float* W2    = (const float*)d_in[1];
    const float* b1    = (const float*)d_in[2];
    const float* b2    = (const float*)d_in[3];
    const float* th0   = (const float*)d_in[4];
    const float* bias0 = (const float*)d_in[5];
    const float* th1   = (const float*)d_in[6];
    const float* bias1 = (const float*)d_in[7];
    const float* th2   = (const float*)d_in[8];
    const float* bias2 = (const float*)d_in[9];
    const float* th3   = (const float*)d_in[10];
    const float* bias3 = (const float*)d_in[11];

    float* out  = (float*)d_out;
    float* out0 = out;
    float* out1 = out + (size_t)NDIM * NDIM * CH;
    float* out2 = out1 + (size_t)NDIM * NDIM * CH;
    float* out3 = out2 + (size_t)NDIM * CH;

    // scratch in the (not-yet-written) out0 region (19.1 MB of 64 MB):
    float* rowpart = out0;                       // [2][16][1024][16]  = 524288
    float* colpart = out0 + 524288;              // [2][128][1024][16] = 4194304
    float* tiletot = out0 + 4718592;             // [2][2048][16]      = 65536

    // workspace: 65,536 floats = 262,144 B (≤ proven budget)
    float* ws = (float*)d_ws;
    float* R0 = ws;                              // 16384 each
    float* C0 = R0 + 16384;
    float* R1 = C0 + 16384;
    float* C1 = R1 + 16384;

    k_fused<<<dim3(16, 128, 2), dim3(256), 0, stream>>>(W1, W2, rowpart, colpart, tiletot);
    k_mid<<<dim3(64), dim3(256), 0, stream>>>(rowpart, colpart, tiletot, b1, b2,
                                              th0, th1, th2, th3,
                                              bias0, bias1, bias2, bias3,
                                              R0, C0, R1, C1, out2, out3);
    k_main<<<dim3(2, NDIM, 2), dim3(256), 0, stream>>>(W1, W2, R0, C0, R1, C1,
                                                       th0, th1 + 2 * 256,
                                                       out0, out1);
}

// Round 12
// 114.189 us; speedup vs baseline: 1.0545x; 1.0106x over previous
//
#include <hip/hip_runtime.h>

#define NDIM 1024
#define CH 16
#define ROW_F4 4096   // float4 per W row (1024*16/4)

__device__ inline float4 f4add(float4 a, float4 b) {
    return make_float4(a.x + b.x, a.y + b.y, a.z + b.z, a.w + b.w);
}
__device__ inline float4 f4zero() { return make_float4(0.f, 0.f, 0.f, 0.f); }

// ---------------------------------------------------------------------------
// k_fused (round-8 proven, verbatim): ONE pass over W -> row partials
// (16 j-chunks), col partials (128 i-chunks), per-tile totals.
// Block = 8 rows x 64 cols. LDS 33 KB -> 4 blocks/CU. Partials in out0.
// ---------------------------------------------------------------------------
__global__ __launch_bounds__(256) void k_fused(const float* __restrict__ W1,
                                               const float* __restrict__ W2,
                                               float* __restrict__ rowpart,
                                               float* __restrict__ colpart,
                                               float* __restrict__ tiletot) {
    int t  = threadIdx.x;
    int jt = blockIdx.x, it = blockIdx.y, z = blockIdx.z;
    const float4* base = (const float4*)(z ? W2 : W1)
                       + (size_t)it * 8 * ROW_F4 + jt * 256 + t;
    __shared__ float4 tile[8][258];
    __shared__ float4 rtot[32];
    float4 colacc = f4zero();
#pragma unroll
    for (int r = 0; r < 8; ++r) {
        float4 v = base[(size_t)r * ROW_F4];
        colacc = f4add(colacc, v);
        tile[r][t] = v;
    }
    ((float4*)colpart)[(size_t)(z * 128 + it) * 4096 + jt * 256 + t] = colacc;
    __syncthreads();
    if (t < 32) {   // row partials: r = t>>2, cq = t&3
        int r = t >> 2, cq = t & 3;
        float4 s = f4zero();
#pragma unroll
        for (int jl = 0; jl < 64; ++jl) s = f4add(s, tile[r][jl * 4 + cq]);
        ((float4*)rowpart)[(size_t)(z * 16 + jt) * 4096 + (it * 8 + r) * 4 + cq] = s;
        rtot[t] = s;
    }
    __syncthreads();
    if (t < 4) {    // tile total (16 ch)
        float4 s = f4zero();
#pragma unroll
        for (int r = 0; r < 8; ++r) s = f4add(s, rtot[r * 4 + t]);
        ((float4*)tiletot)[(size_t)(z * 2048 + it * 16 + jt) * 4 + t] = s;
    }
}

// ---------------------------------------------------------------------------
// k_mid (round-11 proven, verbatim): fully-parallel finalize + global sums +
// all O(N) outputs (64 blocks, 16 i's per block).
// ---------------------------------------------------------------------------
__global__ __launch_bounds__(256) void k_mid(const float* __restrict__ rowpart,
                                             const float* __restrict__ colpart,
                                             const float* __restrict__ tiletot,
                                             const float* __restrict__ b1,
                                             const float* __restrict__ b2,
                                             const float* __restrict__ th0,
                                             const float* __restrict__ th1,
                                             const float* __restrict__ th2,
                                             const float* __restrict__ th3,
                                             const float* __restrict__ bias0,
                                             const float* __restrict__ bias1,
                                             const float* __restrict__ bias2,
                                             const float* __restrict__ bias3,
                                             float* __restrict__ R0, float* __restrict__ C0,
                                             float* __restrict__ R1, float* __restrict__ C1,
                                             float* __restrict__ out2, float* __restrict__ out3) {
    int t  = threadIdx.x;
    int i0 = blockIdx.x * 16;
    __shared__ float sums[64];                  // [W1|W2|b1|b2][16]
    __shared__ float ldsA[2][8][16], ldsB[2][8][16];
    __shared__ float Ars1[16][16], Ars2[16][16], Acs1[16][16], Acs2[16][16];

    // Step A: partial global sums, all 256 threads: (z, p, c)
    {
        int z = t >> 7, c = t & 15, p = (t >> 4) & 7;
        float s = 0.f;
#pragma unroll 8
        for (int m = 0; m < 256; ++m)
            s += tiletot[(size_t)(z * 2048 + p * 256 + m) * 16 + c];
        ldsA[z][p][c] = s;
        const float* bb = z ? b2 : b1;
        s = 0.f;
#pragma unroll 8
        for (int m = 0; m < 128; ++m)
            s += bb[(size_t)(p * 128 + m) * 16 + c];
        ldsB[z][p][c] = s;
    }
    // Step B: finalize row/col sums for this block's 16 i's
    int il = t >> 4, o = t & 15, i = i0 + il;
    {
        float s1 = 0.f, s2 = 0.f, s3 = 0.f, s4 = 0.f;
#pragma unroll 4
        for (int k = 0; k < 16; ++k) {
            s1 += rowpart[(size_t)k * 16384 + i * 16 + o];
            s2 += rowpart[(size_t)(16 + k) * 16384 + i * 16 + o];
        }
#pragma unroll 8
        for (int k = 0; k < 128; ++k) {
            s3 += colpart[(size_t)k * 16384 + i * 16 + o];
            s4 += colpart[(size_t)(128 + k) * 16384 + i * 16 + o];
        }
        Ars1[il][o] = s1; Ars2[il][o] = s2; Acs1[il][o] = s3; Acs2[il][o] = s4;
    }
    __syncthreads();
    if (t < 32) {
        int z = t >> 4, cc = t & 15;
        float r = 0.f;
#pragma unroll
        for (int q = 0; q < 8; ++q) r += ldsA[z][q][cc];
        sums[z * 16 + cc] = r;
    } else if (t < 64) {
        int z = (t - 32) >> 4, cc = t & 15;
        float r = 0.f;
#pragma unroll
        for (int q = 0; q < 8; ++q) r += ldsB[z][q][cc];
        sums[32 + z * 16 + cc] = r;
    }
    __syncthreads();

    // Step C: smalls math. Thread -> (il, o). theta [k][c][o] at k*256+c*16+o
    const float* b1i = b1 + i * 16;
    const float* b2i = b2 + i * 16;
    float r0 = 0.f, c0a = 0.f, r1 = 0.f, c1a = 0.f, o2 = 0.f, o3 = 0.f;
    float k0 = 0.f, k1 = 0.f, k2 = 0.f, k3 = 0.f;
#pragma unroll
    for (int c = 0; c < 16; ++c) {
        float sW1 = sums[c], sW2 = sums[16 + c], sb1 = sums[32 + c], sb2 = sums[48 + c];
        float rs1 = Ars1[il][c], rs2 = Ars2[il][c];
        float cs1 = Acs1[il][c], cs2 = Acs2[il][c];
        float vb1 = b1i[c], vb2 = b2i[c];
        r0  += rs1 * th0[(1 * 16 + c) * 16 + o];
        c0a += cs1 * th0[(2 * 16 + c) * 16 + o]
             + rs2 * th0[(4 * 16 + c) * 16 + o]
             + vb1 * th0[(6 * 16 + c) * 16 + o];
        k0  += sW1 * th0[(3 * 16 + c) * 16 + o] + sW2 * th0[(5 * 16 + c) * 16 + o]
             + sb1 * th0[(7 * 16 + c) * 16 + o] + sb2 * th0[(8 * 16 + c) * 16 + o];
        r1  += cs1 * th1[(0 * 16 + c) * 16 + o]
             + rs2 * th1[(3 * 16 + c) * 16 + o]
             + vb1 * th1[(6 * 16 + c) * 16 + o];
        c1a += cs2 * th1[(4 * 16 + c) * 16 + o]
             + vb2 * th1[(8 * 16 + c) * 16 + o];
        k1  += sW1 * th1[(1 * 16 + c) * 16 + o] + sW2 * th1[(5 * 16 + c) * 16 + o]
             + sb1 * th1[(7 * 16 + c) * 16 + o] + sb2 * th1[(9 * 16 + c) * 16 + o];
        o2  += cs1 * th2[(0 * 16 + c) * 16 + o]
             + rs2 * th2[(2 * 16 + c) * 16 + o]
             + vb1 * th2[(4 * 16 + c) * 16 + o];
        k2  += sW1 * th2[(1 * 16 + c) * 16 + o] + sW2 * th2[(3 * 16 + c) * 16 + o]
             + sb1 * th2[(5 * 16 + c) * 16 + o] + sb2 * th2[(6 * 16 + c) * 16 + o];
        o3  += cs2 * th3[(1 * 16 + c) * 16 + o]
             + vb2 * th3[(4 * 16 + c) * 16 + o];
        k3  += sW1 * th3[(0 * 16 + c) * 16 + o] + sW2 * th3[(2 * 16 + c) * 16 + o]
             + sb1 * th3[(3 * 16 + c) * 16 + o] + sb2 * th3[(5 * 16 + c) * 16 + o];
    }
    int gt = i * 16 + o;
    R0[gt]   = r0;
    C0[gt]   = c0a + k0 + bias0[o];
    R1[gt]   = r1;
    C1[gt]   = c1a + k1 + bias1[o];
    out2[gt] = o2 + k2 + bias2[o];
    out3[gt] = o3 + k3 + bias3[o];
}

// ---------------------------------------------------------------------------
// k_main (round-8 v2 proven, verbatim): LDS-staged CONTIGUOUS global I/O,
// 256 j per block, 21.6 KB LDS -> 7 blocks/CU (the occupancy that v4 lost).
//   out[i,j,:] = W[i,j,:]·θ + R[i] + C[j]
// ---------------------------------------------------------------------------
__global__ __launch_bounds__(256) void k_main(const float* __restrict__ W1,
                                              const float* __restrict__ W2,
                                              const float* __restrict__ R0,
                                              const float* __restrict__ C0,
                                              const float* __restrict__ R1,
                                              const float* __restrict__ C1,
                                              const float* __restrict__ th0,
                                              const float* __restrict__ th1,
                                              float* __restrict__ out0,
                                              float* __restrict__ out1) {
    int z = blockIdx.z;
    const float* W  = z ? W2 : W1;
    const float* R  = z ? R1 : R0;
    const float* Cc = z ? C1 : C0;
    const float* TH = z ? th1 : th0;
    float* out      = z ? out1 : out0;

    int t  = threadIdx.x;
    int i  = blockIdx.y;
    int jb = blockIdx.x * 256;

    __shared__ float4 xs[1280];       // idx = 5*j_local + k (pitch-5)
    __shared__ float  th[256];
    __shared__ float  r[16];
    th[t] = TH[t];
    if (t < 16) r[t] = R[i * 16 + t];

    const float4* Wf4 = (const float4*)W + (size_t)i * 4096 + jb * 4;
    float4*       Of4 = (float4*)out    + (size_t)i * 4096 + jb * 4;

#pragma unroll
    for (int q = 0; q < 4; ++q) {     // contiguous 1KB-per-wave loads
        int g = t + 256 * q;
        xs[5 * (g >> 2) + (g & 3)] = Wf4[g];
    }
    __syncthreads();

    float x[16];
#pragma unroll
    for (int k = 0; k < 4; ++k) {
        float4 v = xs[5 * t + k];
        x[4 * k] = v.x; x[4 * k + 1] = v.y; x[4 * k + 2] = v.z; x[4 * k + 3] = v.w;
    }
    const float4* cj = (const float4*)(Cc + (size_t)(jb + t) * 16);
    float4 c0 = cj[0], c1 = cj[1], c2 = cj[2], c3 = cj[3];
    float acc[16] = {c0.x, c0.y, c0.z, c0.w, c1.x, c1.y, c1.z, c1.w,
                     c2.x, c2.y, c2.z, c2.w, c3.x, c3.y, c3.z, c3.w};
#pragma unroll
    for (int o = 0; o < 16; ++o) acc[o] += r[o];
#pragma unroll
    for (int c = 0; c < 16; ++c) {
        float xv = x[c];
#pragma unroll
        for (int o = 0; o < 16; ++o) acc[o] += xv * th[c * 16 + o];
    }
    __syncthreads();
#pragma unroll
    for (int k = 0; k < 4; ++k)
        xs[5 * t + k] = make_float4(acc[4 * k], acc[4 * k + 1],
                                    acc[4 * k + 2], acc[4 * k + 3]);
    __syncthreads();
#pragma unroll
    for (int q = 0; q < 4; ++q) {     // contiguous stores
        int g = t + 256 * q;
        Of4[g] = xs[5 * (g >> 2) + (g & 3)];
    }
}

extern "C" void kernel_launch(void* const* d_in, const int* in_sizes, int n_in,
                              void* d_out, int out_size, void* d_ws, size_t ws_size,
                              hipStream_t stream) {
    // input order (interleaved theta/bias):
    // 0:W1 1:W2 2:b1 3:b2 4:theta_0 5:bias_0 6:theta_1 7:bias_1
    // 8:theta_2 9:bias_2 10:theta_3 11:bias_3
    const float* W1    = (const float*)d_in[0];
    const float* W2    = (const float*)d_in[1];
    const float* b1    = (const float*)d_in[2];
    const float* b2    = (const float*)d_in[3];
    const float* th0   = (const float*)d_in[4];
    const float* bias0 = (const float*)d_in[5];
    const float* th1   = (const float*)d_in[6];
    const float* bias1 = (const float*)d_in[7];
    const float* th2   = (const float*)d_in[8];
    const float* bias2 = (const float*)d_in[9];
    const float* th3   = (const float*)d_in[10];
    const float* bias3 = (const float*)d_in[11];

    float* out  = (float*)d_out;
    float* out0 = out;
    float* out1 = out + (size_t)NDIM * NDIM * CH;
    float* out2 = out1 + (size_t)NDIM * NDIM * CH;
    float* out3 = out2 + (size_t)NDIM * CH;

    // scratch in the (not-yet-written) out0 region (19.1 MB of 64 MB):
    float* rowpart = out0;                       // [2][16][1024][16]  = 524288
    float* colpart = out0 + 524288;              // [2][128][1024][16] = 4194304
    float* tiletot = out0 + 4718592;             // [2][2048][16]      = 65536

    // workspace: 65,536 floats = 262,144 B (well under proven budget)
    float* ws = (float*)d_ws;
    float* R0 = ws;                              // 16384 each
    float* C0 = R0 + 16384;
    float* R1 = C0 + 16384;
    float* C1 = R1 + 16384;

    k_fused<<<dim3(16, 128, 2), dim3(256), 0, stream>>>(W1, W2, rowpart, colpart, tiletot);
    k_mid<<<dim3(64), dim3(256), 0, stream>>>(rowpart, colpart, tiletot, b1, b2,
                                              th0, th1, th2, th3,
                                              bias0, bias1, bias2, bias3,
                                              R0, C0, R1, C1, out2, out3);
    k_main<<<dim3(4, NDIM, 2), dim3(256), 0, stream>>>(W1, W2, R0, C0, R1, C1,
                                                       th0, th1 + 2 * 256,
                                                       out0, out1);
}

// Round 13
// 90.728 us; speedup vs baseline: 1.3272x; 1.2586x over previous
//
#include <hip/hip_runtime.h>

#define NDIM 1024
#define CH 16
#define ROW_F4 4096   // float4 per W row (1024*16/4)

__device__ inline float4 f4add(float4 a, float4 b) {
    return make_float4(a.x + b.x, a.y + b.y, a.z + b.z, a.w + b.w);
}
__device__ inline float4 f4zero() { return make_float4(0.f, 0.f, 0.f, 0.f); }

// ---------------------------------------------------------------------------
// k_fused (round-8 proven, verbatim): ONE pass over W -> row partials
// (16 j-chunks), col partials (128 i-chunks), per-tile totals.
// Block = 8 rows x 64 cols. LDS 33 KB -> 4 blocks/CU. Partials in out0.
// ---------------------------------------------------------------------------
__global__ __launch_bounds__(256) void k_fused(const float* __restrict__ W1,
                                               const float* __restrict__ W2,
                                               float* __restrict__ rowpart,
                                               float* __restrict__ colpart,
                                               float* __restrict__ tiletot) {
    int t  = threadIdx.x;
    int jt = blockIdx.x, it = blockIdx.y, z = blockIdx.z;
    const float4* base = (const float4*)(z ? W2 : W1)
                       + (size_t)it * 8 * ROW_F4 + jt * 256 + t;
    __shared__ float4 tile[8][258];
    __shared__ float4 rtot[32];
    float4 colacc = f4zero();
#pragma unroll
    for (int r = 0; r < 8; ++r) {
        float4 v = base[(size_t)r * ROW_F4];
        colacc = f4add(colacc, v);
        tile[r][t] = v;
    }
    ((float4*)colpart)[(size_t)(z * 128 + it) * 4096 + jt * 256 + t] = colacc;
    __syncthreads();
    if (t < 32) {   // row partials: r = t>>2, cq = t&3
        int r = t >> 2, cq = t & 3;
        float4 s = f4zero();
#pragma unroll
        for (int jl = 0; jl < 64; ++jl) s = f4add(s, tile[r][jl * 4 + cq]);
        ((float4*)rowpart)[(size_t)(z * 16 + jt) * 4096 + (it * 8 + r) * 4 + cq] = s;
        rtot[t] = s;
    }
    __syncthreads();
    if (t < 4) {    // tile total (16 ch)
        float4 s = f4zero();
#pragma unroll
        for (int r = 0; r < 8; ++r) s = f4add(s, rtot[r * 4 + t]);
        ((float4*)tiletot)[(size_t)(z * 2048 + it * 16 + jt) * 4 + t] = s;
    }
}

// ---------------------------------------------------------------------------
// k_reduce (round-8 proven, verbatim): parallel, coalesced reduction.
// ---------------------------------------------------------------------------
__global__ __launch_bounds__(256) void k_reduce(const float* __restrict__ rowpart,
                                                const float* __restrict__ colpart,
                                                const float* __restrict__ tiletot,
                                                const float* __restrict__ b1,
                                                const float* __restrict__ b2,
                                                float* __restrict__ rowsumF,
                                                float* __restrict__ colsumF,
                                                float* __restrict__ sums) {
    int t = threadIdx.x;
    int b = blockIdx.x;
    if (b < 128) {
        const float4* cp = (const float4*)colpart;
        int o = b * 64 + (t & 63);
        int p = t >> 6;
        int z = o >> 12, rem = o & 4095;
        float4 s = f4zero();
#pragma unroll 8
        for (int k = 0; k < 32; ++k)
            s = f4add(s, cp[(size_t)(z * 128 + p * 32 + k) * 4096 + rem]);
        __shared__ float4 lds[256];
        lds[t] = s;
        __syncthreads();
        if (t < 64) {
            float4 r = f4add(f4add(lds[t], lds[t + 64]),
                             f4add(lds[t + 128], lds[t + 192]));
            ((float4*)colsumF)[o] = r;
        }
    } else if (b < 160) {
        const float4* rp = (const float4*)rowpart;
        int o = (b - 128) * 256 + t;
        int z = o >> 12, rem = o & 4095;
        float4 s = f4zero();
#pragma unroll
        for (int k = 0; k < 16; ++k)
            s = f4add(s, rp[(size_t)(z * 16 + k) * 4096 + rem]);
        ((float4*)rowsumF)[o] = s;
    } else if (b == 160) {
        int c = t & 15, p = (t >> 4) & 7, z = t >> 7;
        float s = 0.f;
#pragma unroll 8
        for (int m = 0; m < 256; ++m)
            s += tiletot[(size_t)(z * 2048 + p * 256 + m) * 16 + c];
        __shared__ float ldsA[2][8][16];
        ldsA[z][p][c] = s;
        __syncthreads();
        if (t < 32) {
            int zz = t >> 4, cc = t & 15;
            float r = 0.f;
#pragma unroll
            for (int q = 0; q < 8; ++q) r += ldsA[zz][q][cc];
            sums[zz * 16 + cc] = r;
        }
    } else {
        int w = b - 161;
        const float* src = w ? b2 : b1;
        int c = t & 15, p = t >> 4;
        float s = 0.f;
#pragma unroll 8
        for (int m = 0; m < 64; ++m)
            s += src[(size_t)(p * 64 + m) * 16 + c];
        __shared__ float ldsB[16][16];
        ldsB[p][c] = s;
        __syncthreads();
        if (t < 16) {
            float r = 0.f;
#pragma unroll
            for (int q = 0; q < 16; ++q) r += ldsB[q][t];
            sums[32 + w * 16 + t] = r;
        }
    }
}

// ---------------------------------------------------------------------------
// k_smalls (round-8 proven, verbatim): all O(N) outputs from finalized sums.
// ---------------------------------------------------------------------------
__global__ __launch_bounds__(256) void k_smalls(const float* __restrict__ rowsum,
                                                const float* __restrict__ colsum,
                                                const float* __restrict__ sums,
                                                const float* __restrict__ b1,
                                                const float* __restrict__ b2,
                                                const float* __restrict__ th0,
                                                const float* __restrict__ th1,
                                                const float* __restrict__ th2,
                                                const float* __restrict__ th3,
                                                const float* __restrict__ bias0,
                                                const float* __restrict__ bias1,
                                                const float* __restrict__ bias2,
                                                const float* __restrict__ bias3,
                                                float* __restrict__ R0, float* __restrict__ C0,
                                                float* __restrict__ R1, float* __restrict__ C1,
                                                float* __restrict__ out2, float* __restrict__ out3) {
    int gt = blockIdx.x * 256 + threadIdx.x;
    int i = gt >> 4, o = gt & 15;
    const float* rs1 = rowsum + i * 16;
    const float* rs2 = rowsum + 16384 + i * 16;
    const float* cs1 = colsum + i * 16;
    const float* cs2 = colsum + 16384 + i * 16;
    const float* b1i = b1 + i * 16;
    const float* b2i = b2 + i * 16;
    float r0 = 0.f, c0a = 0.f, r1 = 0.f, c1a = 0.f, o2 = 0.f, o3 = 0.f;
    float k0 = 0.f, k1 = 0.f, k2 = 0.f, k3 = 0.f;
#pragma unroll
    for (int c = 0; c < 16; ++c) {
        float sW1 = sums[c], sW2 = sums[16 + c], sb1 = sums[32 + c], sb2 = sums[48 + c];
        r0  += rs1[c] * th0[(1 * 16 + c) * 16 + o];
        c0a += cs1[c] * th0[(2 * 16 + c) * 16 + o]
             + rs2[c] * th0[(4 * 16 + c) * 16 + o]
             + b1i[c] * th0[(6 * 16 + c) * 16 + o];
        k0  += sW1 * th0[(3 * 16 + c) * 16 + o] + sW2 * th0[(5 * 16 + c) * 16 + o]
             + sb1 * th0[(7 * 16 + c) * 16 + o] + sb2 * th0[(8 * 16 + c) * 16 + o];
        r1  += cs1[c] * th1[(0 * 16 + c) * 16 + o]
             + rs2[c] * th1[(3 * 16 + c) * 16 + o]
             + b1i[c] * th1[(6 * 16 + c) * 16 + o];
        c1a += cs2[c] * th1[(4 * 16 + c) * 16 + o]
             + b2i[c] * th1[(8 * 16 + c) * 16 + o];
        k1  += sW1 * th1[(1 * 16 + c) * 16 + o] + sW2 * th1[(5 * 16 + c) * 16 + o]
             + sb1 * th1[(7 * 16 + c) * 16 + o] + sb2 * th1[(9 * 16 + c) * 16 + o];
        o2  += cs1[c] * th2[(0 * 16 + c) * 16 + o]
             + rs2[c] * th2[(2 * 16 + c) * 16 + o]
             + b1i[c] * th2[(4 * 16 + c) * 16 + o];
        k2  += sW1 * th2[(1 * 16 + c) * 16 + o] + sW2 * th2[(3 * 16 + c) * 16 + o]
             + sb1 * th2[(5 * 16 + c) * 16 + o] + sb2 * th2[(6 * 16 + c) * 16 + o];
        o3  += cs2[c] * th3[(1 * 16 + c) * 16 + o]
             + b2i[c] * th3[(4 * 16 + c) * 16 + o];
        k3  += sW1 * th3[(0 * 16 + c) * 16 + o] + sW2 * th3[(2 * 16 + c) * 16 + o]
             + sb1 * th3[(3 * 16 + c) * 16 + o] + sb2 * th3[(5 * 16 + c) * 16 + o];
    }
    R0[gt]   = r0;
    C0[gt]   = c0a + k0 + bias0[o];
    R1[gt]   = r1;
    C1[gt]   = c1a + k1 + bias1[o];
    out2[gt] = o2 + k2 + bias2[o];
    out3[gt] = o3 + k3 + bias3[o];
}

// ---------------------------------------------------------------------------
// k_main v5: NO LDS, NO barriers. 4 lanes cooperate per j: lane q owns
// channels 4q..4q+3 (its natural coalesced float4). Quad exchange via
// __shfl_xor masks 1/2/3 (intra-quad DPP). θ column-block (4 outputs x 16
// channels) lives in 64 VGPRs, loaded once per block. C[j] loaded once per
// block. All global I/O is the same 1KB-per-wave coalesced pattern.
//   out[i,j,4q+k] = sum_c W[i,j,c]·θ[c][4q+k] + R[i][4q+k] + C[j][4q+k]
// ---------------------------------------------------------------------------
__global__ __launch_bounds__(256) void k_main(const float* __restrict__ W1,
                                              const float* __restrict__ W2,
                                              const float* __restrict__ R0,
                                              const float* __restrict__ C0,
                                              const float* __restrict__ R1,
                                              const float* __restrict__ C1,
                                              const float* __restrict__ th0,
                                              const float* __restrict__ th1,
                                              float* __restrict__ out0,
                                              float* __restrict__ out1) {
    int z = blockIdx.z;
    const float* __restrict__ W  = z ? W2 : W1;
    const float* __restrict__ R  = z ? R1 : R0;
    const float* __restrict__ Cc = z ? C1 : C0;
    const float* __restrict__ TH = z ? th1 : th0;
    float* __restrict__ out      = z ? out1 : out0;

    int t   = threadIdx.x;
    int q   = t & 3;                       // channel-quad this lane owns
    int jf4 = blockIdx.x * 256 + t;        // f4 index in a row; j = jf4>>2
    int i0  = blockIdx.y * 16;

    // θ registers: th_reg[p][m][k] = θ[channel 4(q^p)+m][output 4q+k]
    float th_reg[4][4][4];
#pragma unroll
    for (int p = 0; p < 4; ++p)
#pragma unroll
        for (int m = 0; m < 4; ++m) {
            float4 v = *(const float4*)(TH + (4 * (q ^ p) + m) * 16 + 4 * q);
            th_reg[p][m][0] = v.x; th_reg[p][m][1] = v.y;
            th_reg[p][m][2] = v.z; th_reg[p][m][3] = v.w;
        }
    float4 cq = ((const float4*)Cc)[jf4];  // C[j] quad q — invariant over i

    const float4* Wf4 = (const float4*)W;
    float4*       Of4 = (float4*)out;

#pragma unroll 2
    for (int ii = 0; ii < 16; ++ii) {
        int i = i0 + ii;
        float4 x  = Wf4[(size_t)i * 4096 + jf4];
        float4 rr = *(const float4*)(R + i * 16 + 4 * q);
        float acc[4] = {cq.x + rr.x, cq.y + rr.y, cq.z + rr.z, cq.w + rr.w};
        float4 xs[4];
        xs[0] = x;
#pragma unroll
        for (int p = 1; p < 4; ++p) {      // intra-quad exchange (DPP)
            xs[p].x = __shfl_xor(x.x, p);
            xs[p].y = __shfl_xor(x.y, p);
            xs[p].z = __shfl_xor(x.z, p);
            xs[p].w = __shfl_xor(x.w, p);
        }
#pragma unroll
        for (int p = 0; p < 4; ++p) {
            float xm0 = xs[p].x, xm1 = xs[p].y, xm2 = xs[p].z, xm3 = xs[p].w;
#pragma unroll
            for (int k = 0; k < 4; ++k)
                acc[k] += xm0 * th_reg[p][0][k] + xm1 * th_reg[p][1][k]
                        + xm2 * th_reg[p][2][k] + xm3 * th_reg[p][3][k];
        }
        Of4[(size_t)i * 4096 + jf4] = make_float4(acc[0], acc[1], acc[2], acc[3]);
    }
}

extern "C" void kernel_launch(void* const* d_in, const int* in_sizes, int n_in,
                              void* d_out, int out_size, void* d_ws, size_t ws_size,
                              hipStream_t stream) {
    // input order (interleaved theta/bias):
    // 0:W1 1:W2 2:b1 3:b2 4:theta_0 5:bias_0 6:theta_1 7:bias_1
    // 8:theta_2 9:bias_2 10:theta_3 11:bias_3
    const float* W1    = (const float*)d_in[0];
    const float* W2    = (const float*)d_in[1];
    const float* b1    = (const float*)d_in[2];
    const float* b2    = (const float*)d_in[3];
    const float* th0   = (const float*)d_in[4];
    const float* bias0 = (const float*)d_in[5];
    const float* th1   = (const float*)d_in[6];
    const float* bias1 = (const float*)d_in[7];
    const float* th2   = (const float*)d_in[8];
    const float* bias2 = (const float*)d_in[9];
    const float* th3   = (const float*)d_in[10];
    const float* bias3 = (const float*)d_in[11];

    float* out  = (float*)d_out;
    float* out0 = out;
    float* out1 = out + (size_t)NDIM * NDIM * CH;
    float* out2 = out1 + (size_t)NDIM * NDIM * CH;
    float* out3 = out2 + (size_t)NDIM * CH;

    // scratch in the (not-yet-written) out0 region (19.1 MB of 64 MB):
    float* rowpart = out0;                       // [2][16][1024][16]  = 524288
    float* colpart = out0 + 524288;              // [2][128][1024][16] = 4194304
    float* tiletot = out0 + 4718592;             // [2][2048][16]      = 65536

    // workspace: 131,136 floats = 524,544 B (proven budget)
    float* ws      = (float*)d_ws;
    float* rowsumF = ws;                         // [2][1024][16] = 32768
    float* colsumF = ws + 32768;                 // [2][1024][16] = 32768
    float* sums    = ws + 65536;                 // [4][16] = 64
    float* R0      = ws + 65600;                 // 16384 each
    float* C0      = R0 + 16384;
    float* R1      = C0 + 16384;
    float* C1      = R1 + 16384;

    k_fused<<<dim3(16, 128, 2), dim3(256), 0, stream>>>(W1, W2, rowpart, colpart, tiletot);
    k_reduce<<<dim3(163), dim3(256), 0, stream>>>(rowpart, colpart, tiletot, b1, b2,
                                                  rowsumF, colsumF, sums);
    k_smalls<<<dim3(64), dim3(256), 0, stream>>>(rowsumF, colsumF, sums, b1, b2,
                                                 th0, th1, th2, th3,
                                                 bias0, bias1, bias2, bias3,
                                                 R0, C0, R1, C1, out2, out3);
    k_main<<<dim3(16, 64, 2), dim3(256), 0, stream>>>(W1, W2, R0, C0, R1, C1,
                                                      th0, th1 + 2 * 256,
                                                      out0, out1);
}

// Round 14
// 89.971 us; speedup vs baseline: 1.3383x; 1.0084x over previous
//
#include <hip/hip_runtime.h>

#define NDIM 1024
#define CH 16
#define ROW_F4 4096   // float4 per W row (1024*16/4)

typedef float fvec4 __attribute__((ext_vector_type(4)));

__device__ inline float4 f4add(float4 a, float4 b) {
    return make_float4(a.x + b.x, a.y + b.y, a.z + b.z, a.w + b.w);
}
__device__ inline float4 f4zero() { return make_float4(0.f, 0.f, 0.f, 0.f); }

// ---------------------------------------------------------------------------
// k_fused (round-8 proven, verbatim): ONE pass over W -> row partials
// (16 j-chunks), col partials (128 i-chunks), per-tile totals.
// Block = 8 rows x 64 cols. LDS 33 KB -> 4 blocks/CU. Partials in out0.
// ---------------------------------------------------------------------------
__global__ __launch_bounds__(256) void k_fused(const float* __restrict__ W1,
                                               const float* __restrict__ W2,
                                               float* __restrict__ rowpart,
                                               float* __restrict__ colpart,
                                               float* __restrict__ tiletot) {
    int t  = threadIdx.x;
    int jt = blockIdx.x, it = blockIdx.y, z = blockIdx.z;
    const float4* base = (const float4*)(z ? W2 : W1)
                       + (size_t)it * 8 * ROW_F4 + jt * 256 + t;
    __shared__ float4 tile[8][258];
    __shared__ float4 rtot[32];
    float4 colacc = f4zero();
#pragma unroll
    for (int r = 0; r < 8; ++r) {
        float4 v = base[(size_t)r * ROW_F4];
        colacc = f4add(colacc, v);
        tile[r][t] = v;
    }
    ((float4*)colpart)[(size_t)(z * 128 + it) * 4096 + jt * 256 + t] = colacc;
    __syncthreads();
    if (t < 32) {   // row partials: r = t>>2, cq = t&3
        int r = t >> 2, cq = t & 3;
        float4 s = f4zero();
#pragma unroll
        for (int jl = 0; jl < 64; ++jl) s = f4add(s, tile[r][jl * 4 + cq]);
        ((float4*)rowpart)[(size_t)(z * 16 + jt) * 4096 + (it * 8 + r) * 4 + cq] = s;
        rtot[t] = s;
    }
    __syncthreads();
    if (t < 4) {    // tile total (16 ch)
        float4 s = f4zero();
#pragma unroll
        for (int r = 0; r < 8; ++r) s = f4add(s, rtot[r * 4 + t]);
        ((float4*)tiletot)[(size_t)(z * 2048 + it * 16 + jt) * 4 + t] = s;
    }
}

// ---------------------------------------------------------------------------
// k_reduce (round-8 proven, verbatim): parallel, coalesced reduction.
// ---------------------------------------------------------------------------
__global__ __launch_bounds__(256) void k_reduce(const float* __restrict__ rowpart,
                                                const float* __restrict__ colpart,
                                                const float* __restrict__ tiletot,
                                                const float* __restrict__ b1,
                                                const float* __restrict__ b2,
                                                float* __restrict__ rowsumF,
                                                float* __restrict__ colsumF,
                                                float* __restrict__ sums) {
    int t = threadIdx.x;
    int b = blockIdx.x;
    if (b < 128) {
        const float4* cp = (const float4*)colpart;
        int o = b * 64 + (t & 63);
        int p = t >> 6;
        int z = o >> 12, rem = o & 4095;
        float4 s = f4zero();
#pragma unroll 8
        for (int k = 0; k < 32; ++k)
            s = f4add(s, cp[(size_t)(z * 128 + p * 32 + k) * 4096 + rem]);
        __shared__ float4 lds[256];
        lds[t] = s;
        __syncthreads();
        if (t < 64) {
            float4 r = f4add(f4add(lds[t], lds[t + 64]),
                             f4add(lds[t + 128], lds[t + 192]));
            ((float4*)colsumF)[o] = r;
        }
    } else if (b < 160) {
        const float4* rp = (const float4*)rowpart;
        int o = (b - 128) * 256 + t;
        int z = o >> 12, rem = o & 4095;
        float4 s = f4zero();
#pragma unroll
        for (int k = 0; k < 16; ++k)
            s = f4add(s, rp[(size_t)(z * 16 + k) * 4096 + rem]);
        ((float4*)rowsumF)[o] = s;
    } else if (b == 160) {
        int c = t & 15, p = (t >> 4) & 7, z = t >> 7;
        float s = 0.f;
#pragma unroll 8
        for (int m = 0; m < 256; ++m)
            s += tiletot[(size_t)(z * 2048 + p * 256 + m) * 16 + c];
        __shared__ float ldsA[2][8][16];
        ldsA[z][p][c] = s;
        __syncthreads();
        if (t < 32) {
            int zz = t >> 4, cc = t & 15;
            float r = 0.f;
#pragma unroll
            for (int q = 0; q < 8; ++q) r += ldsA[zz][q][cc];
            sums[zz * 16 + cc] = r;
        }
    } else {
        int w = b - 161;
        const float* src = w ? b2 : b1;
        int c = t & 15, p = t >> 4;
        float s = 0.f;
#pragma unroll 8
        for (int m = 0; m < 64; ++m)
            s += src[(size_t)(p * 64 + m) * 16 + c];
        __shared__ float ldsB[16][16];
        ldsB[p][c] = s;
        __syncthreads();
        if (t < 16) {
            float r = 0.f;
#pragma unroll
            for (int q = 0; q < 16; ++q) r += ldsB[q][t];
            sums[32 + w * 16 + t] = r;
        }
    }
}

// ---------------------------------------------------------------------------
// k_smalls (round-8 proven, verbatim): all O(N) outputs from finalized sums.
// ---------------------------------------------------------------------------
__global__ __launch_bounds__(256) void k_smalls(const float* __restrict__ rowsum,
                                                const float* __restrict__ colsum,
                                                const float* __restrict__ sums,
                                                const float* __restrict__ b1,
                                                const float* __restrict__ b2,
                                                const float* __restrict__ th0,
                                                const float* __restrict__ th1,
                                                const float* __restrict__ th2,
                                                const float* __restrict__ th3,
                                                const float* __restrict__ bias0,
                                                const float* __restrict__ bias1,
                                                const float* __restrict__ bias2,
                                                const float* __restrict__ bias3,
                                                float* __restrict__ R0, float* __restrict__ C0,
                                                float* __restrict__ R1, float* __restrict__ C1,
                                                float* __restrict__ out2, float* __restrict__ out3) {
    int gt = blockIdx.x * 256 + threadIdx.x;
    int i = gt >> 4, o = gt & 15;
    const float* rs1 = rowsum + i * 16;
    const float* rs2 = rowsum + 16384 + i * 16;
    const float* cs1 = colsum + i * 16;
    const float* cs2 = colsum + 16384 + i * 16;
    const float* b1i = b1 + i * 16;
    const float* b2i = b2 + i * 16;
    float r0 = 0.f, c0a = 0.f, r1 = 0.f, c1a = 0.f, o2 = 0.f, o3 = 0.f;
    float k0 = 0.f, k1 = 0.f, k2 = 0.f, k3 = 0.f;
#pragma unroll
    for (int c = 0; c < 16; ++c) {
        float sW1 = sums[c], sW2 = sums[16 + c], sb1 = sums[32 + c], sb2 = sums[48 + c];
        r0  += rs1[c] * th0[(1 * 16 + c) * 16 + o];
        c0a += cs1[c] * th0[(2 * 16 + c) * 16 + o]
             + rs2[c] * th0[(4 * 16 + c) * 16 + o]
             + b1i[c] * th0[(6 * 16 + c) * 16 + o];
        k0  += sW1 * th0[(3 * 16 + c) * 16 + o] + sW2 * th0[(5 * 16 + c) * 16 + o]
             + sb1 * th0[(7 * 16 + c) * 16 + o] + sb2 * th0[(8 * 16 + c) * 16 + o];
        r1  += cs1[c] * th1[(0 * 16 + c) * 16 + o]
             + rs2[c] * th1[(3 * 16 + c) * 16 + o]
             + b1i[c] * th1[(6 * 16 + c) * 16 + o];
        c1a += cs2[c] * th1[(4 * 16 + c) * 16 + o]
             + b2i[c] * th1[(8 * 16 + c) * 16 + o];
        k1  += sW1 * th1[(1 * 16 + c) * 16 + o] + sW2 * th1[(5 * 16 + c) * 16 + o]
             + sb1 * th1[(7 * 16 + c) * 16 + o] + sb2 * th1[(9 * 16 + c) * 16 + o];
        o2  += cs1[c] * th2[(0 * 16 + c) * 16 + o]
             + rs2[c] * th2[(2 * 16 + c) * 16 + o]
             + b1i[c] * th2[(4 * 16 + c) * 16 + o];
        k2  += sW1 * th2[(1 * 16 + c) * 16 + o] + sW2 * th2[(3 * 16 + c) * 16 + o]
             + sb1 * th2[(5 * 16 + c) * 16 + o] + sb2 * th2[(6 * 16 + c) * 16 + o];
        o3  += cs2[c] * th3[(1 * 16 + c) * 16 + o]
             + b2i[c] * th3[(4 * 16 + c) * 16 + o];
        k3  += sW1 * th3[(0 * 16 + c) * 16 + o] + sW2 * th3[(2 * 16 + c) * 16 + o]
             + sb1 * th3[(3 * 16 + c) * 16 + o] + sb2 * th3[(5 * 16 + c) * 16 + o];
    }
    R0[gt]   = r0;
    C0[gt]   = c0a + k0 + bias0[o];
    R1[gt]   = r1;
    C1[gt]   = c1a + k1 + bias1[o];
    out2[gt] = o2 + k2 + bias2[o];
    out3[gt] = o3 + k3 + bias3[o];
}

// ---------------------------------------------------------------------------
// k_main v6 = v5 + NONTEMPORAL output stores (single change this round).
// Outputs are write-once/never-read: nt stores keep them from evicting W
// from L2/L3, so k_main's W re-reads stay L3-hits.
// ---------------------------------------------------------------------------
__global__ __launch_bounds__(256) void k_main(const float* __restrict__ W1,
                                              const float* __restrict__ W2,
                                              const float* __restrict__ R0,
                                              const float* __restrict__ C0,
                                              const float* __restrict__ R1,
                                              const float* __restrict__ C1,
                                              const float* __restrict__ th0,
                                              const float* __restrict__ th1,
                                              float* __restrict__ out0,
                                              float* __restrict__ out1) {
    int z = blockIdx.z;
    const float* __restrict__ W  = z ? W2 : W1;
    const float* __restrict__ R  = z ? R1 : R0;
    const float* __restrict__ Cc = z ? C1 : C0;
    const float* __restrict__ TH = z ? th1 : th0;
    float* __restrict__ out      = z ? out1 : out0;

    int t   = threadIdx.x;
    int q   = t & 3;                       // channel-quad this lane owns
    int jf4 = blockIdx.x * 256 + t;        // f4 index in a row; j = jf4>>2
    int i0  = blockIdx.y * 16;

    // θ registers: th_reg[p][m][k] = θ[channel 4(q^p)+m][output 4q+k]
    float th_reg[4][4][4];
#pragma unroll
    for (int p = 0; p < 4; ++p)
#pragma unroll
        for (int m = 0; m < 4; ++m) {
            float4 v = *(const float4*)(TH + (4 * (q ^ p) + m) * 16 + 4 * q);
            th_reg[p][m][0] = v.x; th_reg[p][m][1] = v.y;
            th_reg[p][m][2] = v.z; th_reg[p][m][3] = v.w;
        }
    float4 cq = ((const float4*)Cc)[jf4];  // C[j] quad q — invariant over i

    const float4* Wf4 = (const float4*)W;
    fvec4*        Onv = (fvec4*)out;

#pragma unroll 2
    for (int ii = 0; ii < 16; ++ii) {
        int i = i0 + ii;
        float4 x  = Wf4[(size_t)i * 4096 + jf4];
        float4 rr = *(const float4*)(R + i * 16 + 4 * q);
        float acc[4] = {cq.x + rr.x, cq.y + rr.y, cq.z + rr.z, cq.w + rr.w};
        float4 xs[4];
        xs[0] = x;
#pragma unroll
        for (int p = 1; p < 4; ++p) {      // intra-quad exchange (DPP)
            xs[p].x = __shfl_xor(x.x, p);
            xs[p].y = __shfl_xor(x.y, p);
            xs[p].z = __shfl_xor(x.z, p);
            xs[p].w = __shfl_xor(x.w, p);
        }
#pragma unroll
        for (int p = 0; p < 4; ++p) {
            float xm0 = xs[p].x, xm1 = xs[p].y, xm2 = xs[p].z, xm3 = xs[p].w;
#pragma unroll
            for (int k = 0; k < 4; ++k)
                acc[k] += xm0 * th_reg[p][0][k] + xm1 * th_reg[p][1][k]
                        + xm2 * th_reg[p][2][k] + xm3 * th_reg[p][3][k];
        }
        fvec4 val = {acc[0], acc[1], acc[2], acc[3]};
        __builtin_nontemporal_store(val, Onv + (size_t)i * 4096 + jf4);
    }
}

extern "C" void kernel_launch(void* const* d_in, const int* in_sizes, int n_in,
                              void* d_out, int out_size, void* d_ws, size_t ws_size,
                              hipStream_t stream) {
    // input order (interleaved theta/bias):
    // 0:W1 1:W2 2:b1 3:b2 4:theta_0 5:bias_0 6:theta_1 7:bias_1
    // 8:theta_2 9:bias_2 10:theta_3 11:bias_3
    const float* W1    = (const float*)d_in[0];
    const float* W2    = (const float*)d_in[1];
    const float* b1    = (const float*)d_in[2];
    const float* b2    = (const float*)d_in[3];
    const float* th0   = (const float*)d_in[4];
    const float* bias0 = (const float*)d_in[5];
    const float* th1   = (const float*)d_in[6];
    const float* bias1 = (const float*)d_in[7];
    const float* th2   = (const float*)d_in[8];
    const float* bias2 = (const float*)d_in[9];
    const float* th3   = (const float*)d_in[10];
    const float* bias3 = (const float*)d_in[11];

    float* out  = (float*)d_out;
    float* out0 = out;
    float* out1 = out + (size_t)NDIM * NDIM * CH;
    float* out2 = out1 + (size_t)NDIM * NDIM * CH;
    float* out3 = out2 + (size_t)NDIM * CH;

    // scratch in the (not-yet-written) out0 region (19.1 MB of 64 MB):
    float* rowpart = out0;                       // [2][16][1024][16]  = 524288
    float* colpart = out0 + 524288;              // [2][128][1024][16] = 4194304
    float* tiletot = out0 + 4718592;             // [2][2048][16]      = 65536

    // workspace: 131,136 floats = 524,544 B (proven budget)
    float* ws      = (float*)d_ws;
    float* rowsumF = ws;                         // [2][1024][16] = 32768
    float* colsumF = ws + 32768;                 // [2][1024][16] = 32768
    float* sums    = ws + 65536;                 // [4][16] = 64
    float* R0      = ws + 65600;                 // 16384 each
    float* C0      = R0 + 16384;
    float* R1      = C0 + 16384;
    float* C1      = R1 + 16384;

    k_fused<<<dim3(16, 128, 2), dim3(256), 0, stream>>>(W1, W2, rowpart, colpart, tiletot);
    k_reduce<<<dim3(163), dim3(256), 0, stream>>>(rowpart, colpart, tiletot, b1, b2,
                                                  rowsumF, colsumF, sums);
    k_smalls<<<dim3(64), dim3(256), 0, stream>>>(rowsumF, colsumF, sums, b1, b2,
                                                 th0, th1, th2, th3,
                                                 bias0, bias1, bias2, bias3,
                                                 R0, C0, R1, C1, out2, out3);
    k_main<<<dim3(16, 64, 2), dim3(256), 0, stream>>>(W1, W2, R0, C0, R1, C1,
                                                      th0, th1 + 2 * 256,
                                                      out0, out1);
}